// Round 5
// baseline (161.378 us; speedup 1.0000x reference)
//
#include <hip/hip_runtime.h>
#include <hip/hip_bf16.h>

typedef __attribute__((ext_vector_type(4))) float f32x4;
typedef __attribute__((ext_vector_type(16))) float f32x16;
typedef __attribute__((ext_vector_type(8))) short bf16x8;
typedef __attribute__((ext_vector_type(4))) short s16x4;
typedef __attribute__((ext_vector_type(4))) unsigned int u32x4;

#define DEV static __device__ __forceinline__

// fp32 -> bf16 round-to-nearest-even (finite values only)
DEV unsigned short f2b(float f) {
  union { float f; unsigned int u; } v; v.f = f;
  unsigned int u = v.u;
  return (unsigned short)((u + 0x7fffu + ((u >> 16) & 1u)) >> 16);
}

// async global->LDS, 16B per lane; lds base wave-uniform, lanes land at base + lane*16
DEV void gll16(const void* g, void* l) {
  __builtin_amdgcn_global_load_lds((__attribute__((address_space(1))) void*)g,
                                   (__attribute__((address_space(3))) void*)l,
                                   16, 0, 0);
}

// ---------------------------------------------------------------------------
// prep: fp32 -> bf16 conversion + weight repack (unchanged).
// ---------------------------------------------------------------------------
__global__ __launch_bounds__(256) void prep(const float* __restrict__ x,
                                            const float* __restrict__ Wq,
                                            const float* __restrict__ Wk,
                                            const float* __restrict__ Wv,
                                            const float* __restrict__ Wo,
                                            unsigned short* __restrict__ xb,
                                            unsigned short* __restrict__ Wt,
                                            unsigned short* __restrict__ WoT) {
  int id = blockIdx.x * 256 + threadIdx.x;            // 0 .. 3145727
  if (id < 2097152) {                                  // x: 8388608 elems / 4
    f32x4 v = *(const f32x4*)(x + (long)id * 4);
    s16x4 o;
    o.x = (short)f2b(v.x); o.y = (short)f2b(v.y);
    o.z = (short)f2b(v.z); o.w = (short)f2b(v.w);
    *(s16x4*)(xb + (long)id * 4) = o;
  } else {
    int j = id - 2097152;
    if (j < 786432) {                                  // 1536*512
      int n = j >> 9, c = j & 511;
      int proj = n >> 9, hh = (n >> 6) & 7, d = n & 63;
      const float* W = (proj == 0) ? Wq : ((proj == 1) ? Wk : Wv);
      Wt[j] = f2b(W[hh * 32768 + c * 64 + d]);         // W[h][c][d]
    } else {
      int k = j - 786432;                              // 512*512
      int n = k >> 9, c = k & 511;
      WoT[k] = f2b(Wo[c * 512 + n]);
    }
  }
}

// ---------------------------------------------------------------------------
// C[M x N] = A[M x 512] * BT[N x 512]^T   (bf16 in, fp32 accum)
// BK=64, 128x128 tile, 4 waves each 64x64 — now as 2x2 tiles of
// v_mfma_f32_32x32x16_bf16 (16 MFMA/wave/iter, was 32 of 16x16x32).
// A/B frag: row/col = lane&31, k = (lane>>5)*8 + j.
// C/D: col = lane&31, row = (reg&3) + 8*(reg>>2) + 4*(lane>>5)  [m74/m101].
// Global-side XOR swizzle (cg ^ row&7) unchanged — reads stay at the
// 8-bank-cycle b128 minimum (row&7 == l32&7 since tile offsets are %8==0).
// ---------------------------------------------------------------------------
template <int F32OUT>
__global__ __launch_bounds__(256, 2) void gemm_bt(const unsigned short* __restrict__ A,
                                                  const unsigned short* __restrict__ BT,
                                                  void* __restrict__ Cv,
                                                  int N) {
  const int K = 512;
  __shared__ unsigned short As[128 * 64];
  __shared__ unsigned short Bs[128 * 64];

  const int tid = threadIdx.x;
  const int wave = tid >> 6, lane = tid & 63;
  const int l32 = lane & 31, hh = lane >> 5;
  const int wm = wave >> 1, wn = wave & 1;
  const int bm = blockIdx.x, bn = blockIdx.y;

  // staging: 8-row segments of 64 cols; lane i: row i>>3, fetches global
  // col-group (i&7) ^ (row&7), lands at lds cg i&7.
  const int srow = lane >> 3;
  const int scol = ((lane & 7) ^ srow) * 8;

  f32x16 acc[2][2] = {};

  for (int kk = 0; kk < K; kk += 64) {
    __syncthreads();  // previous iteration's LDS reads complete
#pragma unroll
    for (int s = 0; s < 4; s++) {
      int seg = wave * 4 + s;                       // 16 segs x 8 rows = 128 rows
      int row = seg * 8 + srow;
      gll16(A + (long)(bm * 128 + row) * K + kk + scol, As + seg * 512);
      gll16(BT + (long)(bn * 128 + row) * K + kk + scol, Bs + seg * 512);
    }
    __syncthreads();  // drains vmcnt for global_load_lds + barrier

#pragma unroll
    for (int kc = 0; kc < 4; kc++) {                 // 4 x K=16 chunks
      const int swz = (((kc * 2 + hh) ^ (l32 & 7)) * 8);  // un-swizzled 16B group
      bf16x8 af[2], bfv[2];
#pragma unroll
      for (int mt = 0; mt < 2; mt++)
        af[mt] = *(const bf16x8*)(As + (wm * 64 + mt * 32 + l32) * 64 + swz);
#pragma unroll
      for (int nt = 0; nt < 2; nt++)
        bfv[nt] = *(const bf16x8*)(Bs + (wn * 64 + nt * 32 + l32) * 64 + swz);
#pragma unroll
      for (int mt = 0; mt < 2; mt++)
#pragma unroll
        for (int nt = 0; nt < 2; nt++)
          acc[mt][nt] = __builtin_amdgcn_mfma_f32_32x32x16_bf16(af[mt], bfv[nt], acc[mt][nt], 0, 0, 0);
    }
  }

  // epilogue: D elem col = l32, row = (r&3) + 8*(r>>2) + 4*hh per 32x32 tile
#pragma unroll
  for (int mt = 0; mt < 2; mt++) {
#pragma unroll
    for (int nt = 0; nt < 2; nt++) {
      int col = bn * 128 + wn * 64 + nt * 32 + l32;
      int rbase = bm * 128 + wm * 64 + mt * 32 + 4 * hh;
#pragma unroll
      for (int r = 0; r < 16; r++) {
        int row = rbase + (r & 3) + 8 * (r >> 2);
        if (F32OUT)
          ((float*)Cv)[(long)row * N + col] = acc[mt][nt][r];
        else
          ((unsigned short*)Cv)[(long)row * N + col] = f2b(acc[mt][nt][r]);
      }
    }
  }
}

// ---------------------------------------------------------------------------
// Causal attention, one block per (b,h) — unchanged from round 4 (passed;
// rebalanced tile-pair schedule, single barrier, swizzled/padded LDS).
// ---------------------------------------------------------------------------
__global__ __launch_bounds__(256, 2) void attn(const unsigned short* __restrict__ QKV,
                                               unsigned short* __restrict__ AO) {
  const int bh = blockIdx.x;
  const int b = bh >> 3, h = bh & 7;
  const int tid = threadIdx.x;
  const int wave = tid >> 6, lane = tid & 63;
  const int quad = lane >> 4, l16 = lane & 15;

  __shared__ unsigned short Kl[256 * 64];    // [j][cg], stored cg = global cg^(j&7)
  __shared__ unsigned short Vt[64 * 264];    // [d][j], padded rows
  __shared__ unsigned short Pl[4][32 * 40];  // per-wave P [trow][col], padded

  const unsigned short* Qb = QKV + (long)b * 256 * 1536 + h * 64;
  const unsigned short* Kb = Qb + 512;
  const unsigned short* Vb = Qb + 1024;

  // ---- stage K: 32 segs x 8 rows, gll16 with global-side swizzle ----
  {
    int r = lane >> 3, cg = lane & 7;
#pragma unroll
    for (int s = 0; s < 8; s++) {
      int seg = wave * 8 + s;
      gll16(Kb + (long)(seg * 8 + r) * 1536 + ((cg ^ r) * 8), Kl + seg * 512);
    }
  }
  // ---- stage V transposed: thread tid owns V row j=tid ----
  {
    int j = tid;
    const unsigned short* vp = Vb + (long)j * 1536;
#pragma unroll
    for (int g = 0; g < 8; g++) {
      union { u32x4 v; unsigned short s[8]; } d;
      d.v = *(const u32x4*)(vp + g * 8);
#pragma unroll
      for (int q = 0; q < 8; q++)
        Vt[(g * 8 + q) * 264 + j] = d.s[q];
    }
  }
  // ---- Q fragments for this wave's tile pair ----
  const int tiles[2] = {wave, 7 - wave};
  bf16x8 qf[2][2][2];  // [ti][kc][mt]
#pragma unroll
  for (int ti = 0; ti < 2; ti++)
#pragma unroll
    for (int kc = 0; kc < 2; kc++)
#pragma unroll
      for (int mt = 0; mt < 2; mt++)
        qf[ti][kc][mt] = *(const bf16x8*)(Qb +
            (long)(tiles[ti] * 32 + mt * 16 + l16) * 1536 + kc * 32 + quad * 8);

  __syncthreads();  // drains gll16 vmcnt + V/Q visibility; the ONLY barrier

  f32x4 O[2][2][4] = {};      // [ti][mt][dt]
  float lsum[2][2][4] = {};   // [ti][mt][r]
  const float scale = 0.044194173824159216f;  // 1/sqrt(512)

#pragma unroll
  for (int ti = 0; ti < 2; ti++) {
    const int t = tiles[ti];
    for (int c32 = 0; c32 <= t; c32++) {       // wave-uniform trip count
      // ---- S = Q K^T for 32 rows x 32 cols ----
      f32x4 S[2][2] = {};                      // [mt][st]
#pragma unroll
      for (int kc = 0; kc < 2; kc++) {
        bf16x8 kbf[2];
#pragma unroll
        for (int st = 0; st < 2; st++) {
          int jrow = c32 * 32 + st * 16 + l16;
          kbf[st] = *(const bf16x8*)(Kl + jrow * 64 + (((kc * 4 + quad) ^ (jrow & 7)) * 8));
        }
#pragma unroll
        for (int mt = 0; mt < 2; mt++)
#pragma unroll
          for (int st = 0; st < 2; st++)
            S[mt][st] = __builtin_amdgcn_mfma_f32_16x16x32_bf16(qf[ti][kc][mt], kbf[st], S[mt][st], 0, 0, 0);
      }
      // ---- softmax numerator, P -> LDS (C-layout -> row-major) ----
      const bool diag = (c32 == t);
#pragma unroll
      for (int mt = 0; mt < 2; mt++)
#pragma unroll
        for (int st = 0; st < 2; st++)
#pragma unroll
          for (int r = 0; r < 4; r++) {
            int trow = mt * 16 + quad * 4 + r;         // row within 32-row tile
            float p = __expf(S[mt][st][r] * scale);
            if (diag && (st * 16 + l16 > trow)) p = 0.0f;
            lsum[ti][mt][r] += p;
            Pl[wave][trow * 40 + st * 16 + l16] = f2b(p);
          }
      // ---- O += P V  (same-wave LDS RAW: compiler lgkmcnt, no barrier) ----
      bf16x8 pa[2], vbf[4];
#pragma unroll
      for (int mt = 0; mt < 2; mt++)
        pa[mt] = *(const bf16x8*)(&Pl[wave][(mt * 16 + l16) * 40 + quad * 8]);
#pragma unroll
      for (int dt = 0; dt < 4; dt++)
        vbf[dt] = *(const bf16x8*)(Vt + (dt * 16 + l16) * 264 + c32 * 32 + quad * 8);
#pragma unroll
      for (int mt = 0; mt < 2; mt++)
#pragma unroll
        for (int dt = 0; dt < 4; dt++)
          O[ti][mt][dt] = __builtin_amdgcn_mfma_f32_16x16x32_bf16(pa[mt], vbf[dt], O[ti][mt][dt], 0, 0, 0);
    }
  }

  // ---- normalize by row sum (16 lanes of a quad hold one row's 16 cols) ----
  float linv[2][2][4];
#pragma unroll
  for (int ti = 0; ti < 2; ti++)
#pragma unroll
    for (int mt = 0; mt < 2; mt++)
#pragma unroll
      for (int r = 0; r < 4; r++) {
        float s = lsum[ti][mt][r];
        s += __shfl_xor(s, 1); s += __shfl_xor(s, 2);
        s += __shfl_xor(s, 4); s += __shfl_xor(s, 8);
        linv[ti][mt][r] = 1.0f / s;
      }
#pragma unroll
  for (int ti = 0; ti < 2; ti++)
#pragma unroll
    for (int mt = 0; mt < 2; mt++)
#pragma unroll
      for (int dt = 0; dt < 4; dt++)
#pragma unroll
        for (int r = 0; r < 4; r++) {
          int t_ = tiles[ti] * 32 + mt * 16 + quad * 4 + r;
          int d = dt * 16 + l16;
          AO[(long)(b * 256 + t_) * 512 + h * 64 + d] = f2b(O[ti][mt][dt][r] * linv[ti][mt][r]);
        }
}

// ---------------------------------------------------------------------------
extern "C" void kernel_launch(void* const* d_in, const int* in_sizes, int n_in,
                              void* d_out, int out_size, void* d_ws, size_t ws_size,
                              hipStream_t stream) {
  const float* x  = (const float*)d_in[0];   // [16384][512] fp32
  const float* Wq = (const float*)d_in[1];   // [8][512][64] fp32
  const float* Wk = (const float*)d_in[2];
  const float* Wv = (const float*)d_in[3];
  const float* Wo = (const float*)d_in[4];   // [512][512] fp32

  unsigned short* Wt  = (unsigned short*)d_ws;                 // 1536*512
  unsigned short* WoT = Wt + 1536 * 512;                       // 512*512
  unsigned short* xb  = WoT + 512 * 512;                       // 16384*512
  unsigned short* QKV = xb + (long)16384 * 512;                // 16384*1536
  unsigned short* AO  = QKV + (long)16384 * 1536;              // 16384*512
  float* out = (float*)d_out;                                  // [16384][512] fp32

  prep<<<12288, 256, 0, stream>>>(x, Wq, Wk, Wv, Wo, xb, Wt, WoT);

  dim3 g1(128, 12);
  gemm_bt<0><<<g1, 256, 0, stream>>>(xb, Wt, (void*)QKV, 1536);

  attn<<<512, 256, 0, stream>>>(QKV, AO);

  dim3 g2(128, 4);
  gemm_bt<1><<<g2, 256, 0, stream>>>(AO, WoT, (void*)out, 512);
}

// Round 6
// 159.103 us; speedup vs baseline: 1.0143x; 1.0143x over previous
//
#include <hip/hip_runtime.h>
#include <hip/hip_bf16.h>

typedef __attribute__((ext_vector_type(4))) float f32x4;
typedef __attribute__((ext_vector_type(8))) short bf16x8;
typedef __attribute__((ext_vector_type(4))) short s16x4;
typedef __attribute__((ext_vector_type(4))) unsigned int u32x4;

#define DEV static __device__ __forceinline__

// fp32 -> bf16 round-to-nearest-even (finite values only)
DEV unsigned short f2b(float f) {
  union { float f; unsigned int u; } v; v.f = f;
  unsigned int u = v.u;
  return (unsigned short)((u + 0x7fffu + ((u >> 16) & 1u)) >> 16);
}

// raw v_exp_f32: computes 2^x (input already scaled by log2e upstream)
DEV float exp2_raw(float x) {
  float r;
  asm volatile("v_exp_f32 %0, %1" : "=v"(r) : "v"(x));
  return r;
}

// async global->LDS, 16B per lane; lds base wave-uniform, lanes land at base + lane*16
DEV void gll16(const void* g, void* l) {
  __builtin_amdgcn_global_load_lds((__attribute__((address_space(1))) void*)g,
                                   (__attribute__((address_space(3))) void*)l,
                                   16, 0, 0);
}

// ---------------------------------------------------------------------------
// prep: fp32 -> bf16 conversion + weight repack (unchanged).
// ---------------------------------------------------------------------------
__global__ __launch_bounds__(256) void prep(const float* __restrict__ x,
                                            const float* __restrict__ Wq,
                                            const float* __restrict__ Wk,
                                            const float* __restrict__ Wv,
                                            const float* __restrict__ Wo,
                                            unsigned short* __restrict__ xb,
                                            unsigned short* __restrict__ Wt,
                                            unsigned short* __restrict__ WoT) {
  int id = blockIdx.x * 256 + threadIdx.x;            // 0 .. 3145727
  if (id < 2097152) {                                  // x: 8388608 elems / 4
    f32x4 v = *(const f32x4*)(x + (long)id * 4);
    s16x4 o;
    o.x = (short)f2b(v.x); o.y = (short)f2b(v.y);
    o.z = (short)f2b(v.z); o.w = (short)f2b(v.w);
    *(s16x4*)(xb + (long)id * 4) = o;
  } else {
    int j = id - 2097152;
    if (j < 786432) {                                  // 1536*512
      int n = j >> 9, c = j & 511;
      int proj = n >> 9, hh = (n >> 6) & 7, d = n & 63;
      const float* W = (proj == 0) ? Wq : ((proj == 1) ? Wk : Wv);
      Wt[j] = f2b(W[hh * 32768 + c * 64 + d]);         // W[h][c][d]
    } else {
      int k = j - 786432;                              // 512*512
      int n = k >> 9, c = k & 511;
      WoT[k] = f2b(Wo[c * 512 + n]);
    }
  }
}

// ---------------------------------------------------------------------------
// C[M x N] = A[M x 512] * BT[N x 512]^T   (bf16 in, fp32 accum)
// ROUND-4 VERSION (measured best): BK=64, 128x128 tile, 16x16x32 MFMA with
// 16 independent accumulators per wave. 32x32x16 variant (round 5) regressed:
// 4 accumulators -> dependent-issue distance below MFMA latency. Keep 16x16.
// Global-side XOR swizzle on the staged 16B col-group preserves the gll16
// base+lane*16 identity while making LDS reads conflict-free.
// ---------------------------------------------------------------------------
template <int F32OUT>
__global__ __launch_bounds__(256, 2) void gemm_bt(const unsigned short* __restrict__ A,
                                                  const unsigned short* __restrict__ BT,
                                                  void* __restrict__ Cv,
                                                  int N) {
  const int K = 512;
  __shared__ unsigned short As[128 * 64];
  __shared__ unsigned short Bs[128 * 64];

  const int tid = threadIdx.x;
  const int wave = tid >> 6, lane = tid & 63;
  const int quad = lane >> 4, l16 = lane & 15;
  const int wm = wave >> 1, wn = wave & 1;
  const int bm = blockIdx.x, bn = blockIdx.y;

  // staging: 8-row segments of 64 cols; lane i: row i>>3, fetches global
  // col-group (i&7) ^ (row&7), lands at lds cg i&7.
  const int srow = lane >> 3;
  const int scol = ((lane & 7) ^ srow) * 8;

  f32x4 acc[4][4] = {};

  for (int kk = 0; kk < K; kk += 64) {
    __syncthreads();  // previous iteration's LDS reads complete
#pragma unroll
    for (int s = 0; s < 4; s++) {
      int seg = wave * 4 + s;                       // 16 segs x 8 rows = 128 rows
      int row = seg * 8 + srow;
      gll16(A + (long)(bm * 128 + row) * K + kk + scol, As + seg * 512);
      gll16(BT + (long)(bn * 128 + row) * K + kk + scol, Bs + seg * 512);
    }
    __syncthreads();  // drains vmcnt for global_load_lds + barrier

#pragma unroll
    for (int kc = 0; kc < 2; kc++) {
      const int rq = (((kc * 4 + quad) ^ (l16 & 7)) * 8);  // un-swizzle for reader
      bf16x8 af[4], bfv[4];
#pragma unroll
      for (int mt = 0; mt < 4; mt++)
        af[mt] = *(const bf16x8*)(As + (wm * 64 + mt * 16 + l16) * 64 + rq);
#pragma unroll
      for (int nt = 0; nt < 4; nt++)
        bfv[nt] = *(const bf16x8*)(Bs + (wn * 64 + nt * 16 + l16) * 64 + rq);
#pragma unroll
      for (int mt = 0; mt < 4; mt++)
#pragma unroll
        for (int nt = 0; nt < 4; nt++)
          acc[mt][nt] = __builtin_amdgcn_mfma_f32_16x16x32_bf16(af[mt], bfv[nt], acc[mt][nt], 0, 0, 0);
    }
  }

  // epilogue: D elem (row = quad*4 + r, col = l16) within each 16x16 tile
#pragma unroll
  for (int mt = 0; mt < 4; mt++) {
#pragma unroll
    for (int nt = 0; nt < 4; nt++) {
      int row0 = bm * 128 + wm * 64 + mt * 16 + quad * 4;
      int col = bn * 128 + wn * 64 + nt * 16 + l16;
      if (F32OUT) {
        float* cp = (float*)Cv + (long)row0 * N + col;
#pragma unroll
        for (int r = 0; r < 4; r++)
          cp[(long)r * N] = acc[mt][nt][r];
      } else {
        unsigned short* cp = (unsigned short*)Cv + (long)row0 * N + col;
#pragma unroll
        for (int r = 0; r < 4; r++)
          cp[(long)r * N] = f2b(acc[mt][nt][r]);
      }
    }
  }
}

// ---------------------------------------------------------------------------
// Causal attention, one block per (b,h). Round-4 structure (rebalanced
// tile-pair schedule, single barrier) + 2 micro-opts:
//  - exp via raw v_exp_f32 with scale*log2e folded into one constant
//  - V-transpose staged with packed ds_write_b32 row-pairs (32 vs 64 writes)
// ---------------------------------------------------------------------------
__global__ __launch_bounds__(256, 2) void attn(const unsigned short* __restrict__ QKV,
                                               unsigned short* __restrict__ AO) {
  const int bh = blockIdx.x;
  const int b = bh >> 3, h = bh & 7;
  const int tid = threadIdx.x;
  const int wave = tid >> 6, lane = tid & 63;
  const int quad = lane >> 4, l16 = lane & 15;

  __shared__ unsigned short Kl[256 * 64];    // [j][cg], stored cg = global cg^(j&7)
  __shared__ unsigned short Vt[64 * 264];    // [d][j], padded rows
  __shared__ unsigned short Pl[4][32 * 40];  // per-wave P [trow][col], padded

  const unsigned short* Qb = QKV + (long)b * 256 * 1536 + h * 64;
  const unsigned short* Kb = Qb + 512;
  const unsigned short* Vb = Qb + 1024;

  // ---- stage K: 32 segs x 8 rows, gll16 with global-side swizzle ----
  {
    int r = lane >> 3, cg = lane & 7;
#pragma unroll
    for (int s = 0; s < 8; s++) {
      int seg = wave * 8 + s;
      gll16(Kb + (long)(seg * 8 + r) * 1536 + ((cg ^ r) * 8), Kl + seg * 512);
    }
  }
  // ---- stage V transposed, packed: thread i owns rows {2jp, 2jp+1}, 32 d's ----
  {
    int jp = tid & 127, dh = tid >> 7;       // pair index, d-half
    int j0 = jp * 2;
    const unsigned short* vp0 = Vb + (long)j0 * 1536 + dh * 32;
    const unsigned short* vp1 = vp0 + 1536;
#pragma unroll
    for (int g = 0; g < 4; g++) {
      union { u32x4 v; unsigned short s[8]; } a, c;
      a.v = *(const u32x4*)(vp0 + g * 8);
      c.v = *(const u32x4*)(vp1 + g * 8);
#pragma unroll
      for (int q = 0; q < 8; q++) {
        int d = dh * 32 + g * 8 + q;
        unsigned int pk = (unsigned int)a.s[q] | ((unsigned int)c.s[q] << 16);
        *(unsigned int*)(Vt + d * 264 + j0) = pk;
      }
    }
  }
  // ---- Q fragments for this wave's tile pair ----
  const int tiles[2] = {wave, 7 - wave};
  bf16x8 qf[2][2][2];  // [ti][kc][mt]
#pragma unroll
  for (int ti = 0; ti < 2; ti++)
#pragma unroll
    for (int kc = 0; kc < 2; kc++)
#pragma unroll
      for (int mt = 0; mt < 2; mt++)
        qf[ti][kc][mt] = *(const bf16x8*)(Qb +
            (long)(tiles[ti] * 32 + mt * 16 + l16) * 1536 + kc * 32 + quad * 8);

  __syncthreads();  // drains gll16 vmcnt + V/Q visibility; the ONLY barrier

  f32x4 O[2][2][4] = {};      // [ti][mt][dt]
  float lsum[2][2][4] = {};   // [ti][mt][r]
  const float sl2e = 0.06375871575f;  // (1/sqrt(512)) * log2(e)

#pragma unroll
  for (int ti = 0; ti < 2; ti++) {
    const int t = tiles[ti];
    for (int c32 = 0; c32 <= t; c32++) {       // wave-uniform trip count
      // ---- S = Q K^T for 32 rows x 32 cols ----
      f32x4 S[2][2] = {};                      // [mt][st]
#pragma unroll
      for (int kc = 0; kc < 2; kc++) {
        bf16x8 kbf[2];
#pragma unroll
        for (int st = 0; st < 2; st++) {
          int jrow = c32 * 32 + st * 16 + l16;
          kbf[st] = *(const bf16x8*)(Kl + jrow * 64 + (((kc * 4 + quad) ^ (jrow & 7)) * 8));
        }
#pragma unroll
        for (int mt = 0; mt < 2; mt++)
#pragma unroll
          for (int st = 0; st < 2; st++)
            S[mt][st] = __builtin_amdgcn_mfma_f32_16x16x32_bf16(qf[ti][kc][mt], kbf[st], S[mt][st], 0, 0, 0);
      }
      // ---- V fragments for this chunk (independent of P, issue early) ----
      bf16x8 vbf[4];
#pragma unroll
      for (int dt = 0; dt < 4; dt++)
        vbf[dt] = *(const bf16x8*)(Vt + (dt * 16 + l16) * 264 + c32 * 32 + quad * 8);
      // ---- softmax numerator, P -> LDS (C-layout -> row-major) ----
      const bool diag = (c32 == t);
#pragma unroll
      for (int mt = 0; mt < 2; mt++)
#pragma unroll
        for (int st = 0; st < 2; st++)
#pragma unroll
          for (int r = 0; r < 4; r++) {
            int trow = mt * 16 + quad * 4 + r;         // row within 32-row tile
            float p = exp2_raw(S[mt][st][r] * sl2e);   // 2^(s*scale*log2e)=e^(s*scale)
            if (diag && (st * 16 + l16 > trow)) p = 0.0f;
            lsum[ti][mt][r] += p;
            Pl[wave][trow * 40 + st * 16 + l16] = f2b(p);
          }
      // ---- O += P V  (same-wave LDS RAW: compiler lgkmcnt, no barrier) ----
      bf16x8 pa[2];
#pragma unroll
      for (int mt = 0; mt < 2; mt++)
        pa[mt] = *(const bf16x8*)(&Pl[wave][(mt * 16 + l16) * 40 + quad * 8]);
#pragma unroll
      for (int mt = 0; mt < 2; mt++)
#pragma unroll
        for (int dt = 0; dt < 4; dt++)
          O[ti][mt][dt] = __builtin_amdgcn_mfma_f32_16x16x32_bf16(pa[mt], vbf[dt], O[ti][mt][dt], 0, 0, 0);
    }
  }

  // ---- normalize by row sum (16 lanes of a quad hold one row's 16 cols) ----
  float linv[2][2][4];
#pragma unroll
  for (int ti = 0; ti < 2; ti++)
#pragma unroll
    for (int mt = 0; mt < 2; mt++)
#pragma unroll
      for (int r = 0; r < 4; r++) {
        float s = lsum[ti][mt][r];
        s += __shfl_xor(s, 1); s += __shfl_xor(s, 2);
        s += __shfl_xor(s, 4); s += __shfl_xor(s, 8);
        linv[ti][mt][r] = 1.0f / s;
      }
#pragma unroll
  for (int ti = 0; ti < 2; ti++)
#pragma unroll
    for (int mt = 0; mt < 2; mt++)
#pragma unroll
      for (int dt = 0; dt < 4; dt++)
#pragma unroll
        for (int r = 0; r < 4; r++) {
          int t_ = tiles[ti] * 32 + mt * 16 + quad * 4 + r;
          int d = dt * 16 + l16;
          AO[(long)(b * 256 + t_) * 512 + h * 64 + d] = f2b(O[ti][mt][dt][r] * linv[ti][mt][r]);
        }
}

// ---------------------------------------------------------------------------
extern "C" void kernel_launch(void* const* d_in, const int* in_sizes, int n_in,
                              void* d_out, int out_size, void* d_ws, size_t ws_size,
                              hipStream_t stream) {
  const float* x  = (const float*)d_in[0];   // [16384][512] fp32
  const float* Wq = (const float*)d_in[1];   // [8][512][64] fp32
  const float* Wk = (const float*)d_in[2];
  const float* Wv = (const float*)d_in[3];
  const float* Wo = (const float*)d_in[4];   // [512][512] fp32

  unsigned short* Wt  = (unsigned short*)d_ws;                 // 1536*512
  unsigned short* WoT = Wt + 1536 * 512;                       // 512*512
  unsigned short* xb  = WoT + 512 * 512;                       // 16384*512
  unsigned short* QKV = xb + (long)16384 * 512;                // 16384*1536
  unsigned short* AO  = QKV + (long)16384 * 1536;              // 16384*512
  float* out = (float*)d_out;                                  // [16384][512] fp32

  prep<<<12288, 256, 0, stream>>>(x, Wq, Wk, Wv, Wo, xb, Wt, WoT);

  dim3 g1(128, 12);
  gemm_bt<0><<<g1, 256, 0, stream>>>(xb, Wt, (void*)QKV, 1536);

  attn<<<512, 256, 0, stream>>>(QKV, AO);

  dim3 g2(128, 4);
  gemm_bt<1><<<g2, 256, 0, stream>>>(AO, WoT, (void*)out, 512);
}